// Round 7
// baseline (330.682 us; speedup 1.0000x reference)
//
#include <hip/hip_runtime.h>
#include <math.h>

#define NEG_SLOPE 0.2f

typedef short short8 __attribute__((ext_vector_type(8)));
typedef float floatx4 __attribute__((ext_vector_type(4)));

static __device__ __forceinline__ float bf2f(unsigned short u) {
  return __uint_as_float(((unsigned int)u) << 16);
}
static __device__ __forceinline__ unsigned short f2bf(float f) {
  unsigned int u = __float_as_uint(f);
  u = (u + 0x7fffu + ((u >> 16) & 1u)) >> 16;  // RNE
  return (unsigned short)u;
}
static __device__ __forceinline__ unsigned int pack2(float a, float b) {
  return (unsigned int)f2bf(a) | ((unsigned int)f2bf(b) << 16);
}

// ---------- prep: W1 -> bf16 transposed + deg init ----------
__global__ void prep_kernel(const float* __restrict__ W1, unsigned short* __restrict__ W1t,
                            int* __restrict__ deg, int N) {
  int i = blockIdx.x * 256 + threadIdx.x;
  if (i < 32768) {
    int k = i >> 6, c = i & 63;
    W1t[c * 512 + k] = f2bf(W1[i]);
  }
  int j = i - 32768;
  if (j >= 0 && j < N) deg[j] = 1;  // self-loop
}

// ---------- GEMM1 via MFMA, double-buffered LDS ----------
__global__ __launch_bounds__(256) void gemm1_mfma(const float* __restrict__ A,
                                                  const unsigned short* __restrict__ W1t,
                                                  const float* __restrict__ att_src,
                                                  const float* __restrict__ att_dst,
                                                  unsigned short* __restrict__ xlb,
                                                  float* __restrict__ a_src,
                                                  float* __restrict__ a_dst, int M) {
  __shared__ unsigned short As[2][64 * 72];  // pad 72: 2-way bank alias = free
  __shared__ unsigned short Bs[2][64 * 72];
  int tid = threadIdx.x;
  int w = tid >> 6, lane = tid & 63;
  int q = lane >> 4, cl = lane & 15;
  int row0 = blockIdx.x << 6;
  floatx4 acc[4] = {};

  int sr = tid >> 2;            // staging row/col 0..63
  int skq = (tid & 3) << 4;     // k offset 0,16,32,48
  int arow = row0 + sr;
  const float* Aptr = A + (size_t)arow * 512 + skq;
  const unsigned short* Bptr = W1t + sr * 512 + skq;
  unsigned short* AsW0 = &As[0][sr * 72 + skq];
  unsigned short* BsW0 = &Bs[0][sr * 72 + skq];
  unsigned short* AsW1 = &As[1][sr * 72 + skq];
  unsigned short* BsW1 = &Bs[1][sr * 72 + skq];

  float4 f0 = make_float4(0.f, 0.f, 0.f, 0.f), f1 = f0, f2 = f0, f3 = f0;
  uint4 b0, b1;
  if (arow < M) {
    f0 = *(const float4*)(Aptr);
    f1 = *(const float4*)(Aptr + 4);
    f2 = *(const float4*)(Aptr + 8);
    f3 = *(const float4*)(Aptr + 12);
  }
  b0 = *(const uint4*)(Bptr);
  b1 = *(const uint4*)(Bptr + 8);
  {
    uint4 a0, a1;
    a0.x = pack2(f0.x, f0.y); a0.y = pack2(f0.z, f0.w);
    a0.z = pack2(f1.x, f1.y); a0.w = pack2(f1.z, f1.w);
    a1.x = pack2(f2.x, f2.y); a1.y = pack2(f2.z, f2.w);
    a1.z = pack2(f3.x, f3.y); a1.w = pack2(f3.z, f3.w);
    *(uint4*)(AsW0) = a0;
    *(uint4*)(AsW0 + 8) = a1;
    *(uint4*)(BsW0) = b0;
    *(uint4*)(BsW0 + 8) = b1;
  }
  __syncthreads();

  for (int c = 0; c < 8; ++c) {
    int cur = c & 1;
    if (c < 7) {
      int k0 = (c + 1) << 6;
      if (arow < M) {
        f0 = *(const float4*)(Aptr + k0);
        f1 = *(const float4*)(Aptr + k0 + 4);
        f2 = *(const float4*)(Aptr + k0 + 8);
        f3 = *(const float4*)(Aptr + k0 + 12);
      }
      b0 = *(const uint4*)(Bptr + k0);
      b1 = *(const uint4*)(Bptr + k0 + 8);
    }
#pragma unroll
    for (int kk = 0; kk < 2; ++kk) {
      short8 af = *(const short8*)(&As[cur][(w * 16 + cl) * 72 + kk * 32 + q * 8]);
#pragma unroll
      for (int t = 0; t < 4; ++t) {
        short8 bf = *(const short8*)(&Bs[cur][(t * 16 + cl) * 72 + kk * 32 + q * 8]);
        acc[t] = __builtin_amdgcn_mfma_f32_16x16x32_bf16(af, bf, acc[t], 0, 0, 0);
      }
    }
    if (c < 7) {
      uint4 a0, a1;
      a0.x = pack2(f0.x, f0.y); a0.y = pack2(f0.z, f0.w);
      a0.z = pack2(f1.x, f1.y); a0.w = pack2(f1.z, f1.w);
      a1.x = pack2(f2.x, f2.y); a1.y = pack2(f2.z, f2.w);
      a1.z = pack2(f3.x, f3.y); a1.w = pack2(f3.z, f3.w);
      unsigned short* AsW = cur ? AsW0 : AsW1;
      unsigned short* BsW = cur ? BsW0 : BsW1;
      *(uint4*)(AsW) = a0;
      *(uint4*)(AsW + 8) = a1;
      *(uint4*)(BsW) = b0;
      *(uint4*)(BsW + 8) = b1;
      __syncthreads();
    }
  }

  // epilogue: C/D layout col = cl (within tile), row = q*4 + reg
  float asv[4], adv[4];
#pragma unroll
  for (int t = 0; t < 4; ++t) {
    asv[t] = att_src[t * 16 + cl];
    adv[t] = att_dst[t * 16 + cl];
  }
#pragma unroll
  for (int reg = 0; reg < 4; ++reg) {
    int r = row0 + w * 16 + q * 4 + reg;
    bool ok = r < M;
#pragma unroll
    for (int t = 0; t < 4; ++t) {
      float v = acc[t][reg];
      if (ok) xlb[(size_t)r * 64 + t * 16 + cl] = f2bf(v);
      float ps = v * asv[t];
      float pd = v * adv[t];
      ps += __shfl_xor(ps, 1); pd += __shfl_xor(pd, 1);
      ps += __shfl_xor(ps, 2); pd += __shfl_xor(pd, 2);
      ps += __shfl_xor(ps, 4); pd += __shfl_xor(pd, 4);
      if (ok && (cl & 7) == 0) {
        int h = t * 2 + (cl >> 3);
        a_src[r * 8 + h] = ps;
        a_dst[r * 8 + h] = pd;
      }
    }
  }
}

// ---------- XCD-sliced histogram ----------
__global__ __launch_bounds__(256) void deg_hist_sliced(const int* __restrict__ ei,
                                                       int* __restrict__ deg,
                                                       int E, int N, int ipc) {
  int slice = blockIdx.x & 7;
  int chunk = blockIdx.x >> 3;
  int lo = (int)(((long long)slice * N) >> 3);
  int hi = (int)(((long long)(slice + 1) * N) >> 3);
  int beg = chunk * ipc;
  int end = min(beg + ipc, E);
  for (int i = beg + threadIdx.x; i < end; i += 256) {
    int d = ei[E + i];
    if (d >= lo && d < hi) atomicAdd(&deg[d], 1);
  }
}

// ---------- hierarchical scan ----------
__global__ __launch_bounds__(256) void partial_sums(const int* __restrict__ deg,
                                                    int* __restrict__ partials, int N) {
  __shared__ int ws[4];
  int base = blockIdx.x * 512;
  int tid = threadIdx.x;
  int i0 = base + tid * 2;
  int s = 0;
  if (i0 < N) s += deg[i0];
  if (i0 + 1 < N) s += deg[i0 + 1];
#pragma unroll
  for (int off = 32; off >= 1; off >>= 1) s += __shfl_xor(s, off, 64);
  if ((tid & 63) == 0) ws[tid >> 6] = s;
  __syncthreads();
  if (tid == 0) partials[blockIdx.x] = ws[0] + ws[1] + ws[2] + ws[3];
}

__global__ __launch_bounds__(256) void scan_partials(const int* __restrict__ partials,
                                                     int* __restrict__ blockoff,
                                                     int* __restrict__ rowptr, int nb, int N) {
  __shared__ int sums[256];
  int tid = threadIdx.x;
  int chunk = (nb + 255) >> 8;
  int start = tid * chunk, end = min(start + chunk, nb);
  int s = 0;
  for (int i = start; i < end; ++i) s += partials[i];
  sums[tid] = s;
  __syncthreads();
  for (int off = 1; off < 256; off <<= 1) {
    int t = (tid >= off) ? sums[tid - off] : 0;
    __syncthreads();
    sums[tid] += t;
    __syncthreads();
  }
  int run = (tid == 0) ? 0 : sums[tid - 1];
  for (int i = start; i < end; ++i) {
    blockoff[i] = run;
    run += partials[i];
  }
  if (tid == 255) rowptr[N] = sums[255];
}

__global__ __launch_bounds__(256) void scan_blocks(const int* __restrict__ deg,
                                                   const int* __restrict__ blockoff,
                                                   int* __restrict__ rowptr,
                                                   int* __restrict__ cursor, int N) {
  __shared__ int wavesum[4];
  int base = blockIdx.x * 512;
  int tid = threadIdx.x;
  int lane = tid & 63, wv = tid >> 6;
  int i0 = base + tid * 2;
  int d0 = (i0 < N) ? deg[i0] : 0;
  int d1 = (i0 + 1 < N) ? deg[i0 + 1] : 0;
  int s = d0 + d1;
  int v = s;
#pragma unroll
  for (int off = 1; off < 64; off <<= 1) {
    int t = __shfl_up(v, off, 64);
    if (lane >= off) v += t;
  }
  if (lane == 63) wavesum[wv] = v;
  __syncthreads();
  int woff = 0;
  for (int w = 0; w < wv; ++w) woff += wavesum[w];
  int excl = v - s + woff + blockoff[blockIdx.x];
  if (i0 < N) { rowptr[i0] = excl; cursor[i0] = excl; }
  if (i0 + 1 < N) { rowptr[i0 + 1] = excl + d0; cursor[i0 + 1] = excl + d0; }
}

// ---------- XCD-sliced scatter ----------
__global__ __launch_bounds__(256) void scatter_sliced(const int* __restrict__ ei,
                                                      int* __restrict__ cursor,
                                                      int* __restrict__ srcs,
                                                      int E, int N, int ipc) {
  int slice = blockIdx.x & 7;
  int chunk = blockIdx.x >> 3;
  int lo = (int)(((long long)slice * N) >> 3);
  int hi = (int)(((long long)(slice + 1) * N) >> 3);
  int total = E + N;
  int beg = chunk * ipc;
  int end = min(beg + ipc, total);
  for (int i = beg + threadIdx.x; i < end; i += 256) {
    int d = (i < E) ? ei[E + i] : (i - E);
    if (d >= lo && d < hi) {
      int s = (i < E) ? ei[i] : d;
      int pos = atomicAdd(&cursor[d], 1);
      srcs[pos] = s;
    }
  }
}

// ---------- layer-1 aggregation + fused layer-2 GEMM/att-coef ----------
// 4 waves/block = 4 nodes; wave lane = channel, head = lane>>3.
// Epilogue: xl2 = (agg1 + bias1) @ W2 computed in-block (W2 in LDS).
__global__ __launch_bounds__(256) void agg1_fused(const int* __restrict__ rowptr,
                                                  const int* __restrict__ srcs,
                                                  const float* __restrict__ a_src,
                                                  const float* __restrict__ a_dst,
                                                  const unsigned short* __restrict__ xlb,
                                                  const float* __restrict__ bias1,
                                                  const float* __restrict__ W2,
                                                  const float* __restrict__ att_src2,
                                                  const float* __restrict__ att_dst2,
                                                  float* __restrict__ xl2,
                                                  float* __restrict__ a_src2,
                                                  float* __restrict__ a_dst2, int N) {
  __shared__ float W2s[64 * 16];
  __shared__ float hs[4][72];
  int tid = threadIdx.x;
  for (int i = tid; i < 1024; i += 256) W2s[i] = W2[i];
  int wv = tid >> 6, lane = tid & 63;
  int node0 = blockIdx.x << 2;
  int node = node0 + wv;
  if (node < N) {
    int h = lane >> 3;
    int beg = rowptr[node], end = rowptr[node + 1];
    float ad = a_dst[node * 8 + h];
    float den = 0.f, acc = 0.f;
    int p = beg;
    for (; p + 8 <= end; p += 8) {
      int s0 = srcs[p], s1 = srcs[p + 1], s2 = srcs[p + 2], s3 = srcs[p + 3];
      int s4 = srcs[p + 4], s5 = srcs[p + 5], s6 = srcs[p + 6], s7 = srcs[p + 7];
      float a0 = a_src[s0 * 8 + h], a1 = a_src[s1 * 8 + h];
      float a2 = a_src[s2 * 8 + h], a3 = a_src[s3 * 8 + h];
      float a4 = a_src[s4 * 8 + h], a5 = a_src[s5 * 8 + h];
      float a6 = a_src[s6 * 8 + h], a7 = a_src[s7 * 8 + h];
      float x0 = bf2f(xlb[(size_t)s0 * 64 + lane]);
      float x1 = bf2f(xlb[(size_t)s1 * 64 + lane]);
      float x2 = bf2f(xlb[(size_t)s2 * 64 + lane]);
      float x3 = bf2f(xlb[(size_t)s3 * 64 + lane]);
      float x4 = bf2f(xlb[(size_t)s4 * 64 + lane]);
      float x5 = bf2f(xlb[(size_t)s5 * 64 + lane]);
      float x6 = bf2f(xlb[(size_t)s6 * 64 + lane]);
      float x7 = bf2f(xlb[(size_t)s7 * 64 + lane]);
      a0 += ad; a1 += ad; a2 += ad; a3 += ad;
      a4 += ad; a5 += ad; a6 += ad; a7 += ad;
      a0 = a0 >= 0.f ? a0 : NEG_SLOPE * a0;
      a1 = a1 >= 0.f ? a1 : NEG_SLOPE * a1;
      a2 = a2 >= 0.f ? a2 : NEG_SLOPE * a2;
      a3 = a3 >= 0.f ? a3 : NEG_SLOPE * a3;
      a4 = a4 >= 0.f ? a4 : NEG_SLOPE * a4;
      a5 = a5 >= 0.f ? a5 : NEG_SLOPE * a5;
      a6 = a6 >= 0.f ? a6 : NEG_SLOPE * a6;
      a7 = a7 >= 0.f ? a7 : NEG_SLOPE * a7;
      float w0 = __expf(a0), w1 = __expf(a1), w2 = __expf(a2), w3 = __expf(a3);
      float w4 = __expf(a4), w5 = __expf(a5), w6 = __expf(a6), w7 = __expf(a7);
      den += ((w0 + w1) + (w2 + w3)) + ((w4 + w5) + (w6 + w7));
      acc += w0 * x0 + w1 * x1 + w2 * x2 + w3 * x3;
      acc += w4 * x4 + w5 * x5 + w6 * x6 + w7 * x7;
    }
    for (; p < end; ++p) {
      int s = srcs[p];
      float a = a_src[s * 8 + h] + ad;
      a = a >= 0.f ? a : NEG_SLOPE * a;
      float w = __expf(a);
      den += w;
      acc += w * bf2f(xlb[(size_t)s * 64 + lane]);
    }
    hs[wv][lane] = acc / (den + 1e-16f) + bias1[lane];
  }
  __syncthreads();
  if (tid < 64) {
    int nd = tid >> 4, c = tid & 15;
    int n = node0 + nd;
    if (n < N) {
      float sum = 0.f;
#pragma unroll
      for (int k = 0; k < 64; ++k) sum += hs[nd][k] * W2s[k * 16 + c];
      xl2[(size_t)n * 16 + c] = sum;
      float ps = sum * att_src2[c];
      float pd = sum * att_dst2[c];
#pragma unroll
      for (int w = 8; w >= 1; w >>= 1) {
        ps += __shfl_xor(ps, w, 16);
        pd += __shfl_xor(pd, w, 16);
      }
      if (c == 0) {
        a_src2[n] = ps;
        a_dst2[n] = pd;
      }
    }
  }
}

// ---------- layer-2 aggregation + bias2 + ELU + log_softmax ----------
__global__ __launch_bounds__(256) void agg2_fin(const int* __restrict__ rowptr,
                                                const int* __restrict__ srcs,
                                                const float* __restrict__ a_src2,
                                                const float* __restrict__ a_dst2,
                                                const float* __restrict__ xl2,
                                                const float* __restrict__ bias2,
                                                float* __restrict__ out, int N) {
  int t = blockIdx.x * blockDim.x + threadIdx.x;
  int node = t >> 4;
  int c = t & 15;
  if (node >= N) return;
  int beg = rowptr[node], end = rowptr[node + 1];
  float ad = a_dst2[node];
  float den = 0.f, acc = 0.f;
  int p = beg;
  for (; p + 8 <= end; p += 8) {
    int s0 = srcs[p], s1 = srcs[p + 1], s2 = srcs[p + 2], s3 = srcs[p + 3];
    int s4 = srcs[p + 4], s5 = srcs[p + 5], s6 = srcs[p + 6], s7 = srcs[p + 7];
    float a0 = a_src2[s0], a1 = a_src2[s1], a2 = a_src2[s2], a3 = a_src2[s3];
    float a4 = a_src2[s4], a5 = a_src2[s5], a6 = a_src2[s6], a7 = a_src2[s7];
    float x0 = xl2[(size_t)s0 * 16 + c], x1 = xl2[(size_t)s1 * 16 + c];
    float x2 = xl2[(size_t)s2 * 16 + c], x3 = xl2[(size_t)s3 * 16 + c];
    float x4 = xl2[(size_t)s4 * 16 + c], x5 = xl2[(size_t)s5 * 16 + c];
    float x6 = xl2[(size_t)s6 * 16 + c], x7 = xl2[(size_t)s7 * 16 + c];
    a0 += ad; a1 += ad; a2 += ad; a3 += ad;
    a4 += ad; a5 += ad; a6 += ad; a7 += ad;
    a0 = a0 >= 0.f ? a0 : NEG_SLOPE * a0;
    a1 = a1 >= 0.f ? a1 : NEG_SLOPE * a1;
    a2 = a2 >= 0.f ? a2 : NEG_SLOPE * a2;
    a3 = a3 >= 0.f ? a3 : NEG_SLOPE * a3;
    a4 = a4 >= 0.f ? a4 : NEG_SLOPE * a4;
    a5 = a5 >= 0.f ? a5 : NEG_SLOPE * a5;
    a6 = a6 >= 0.f ? a6 : NEG_SLOPE * a6;
    a7 = a7 >= 0.f ? a7 : NEG_SLOPE * a7;
    float w0 = __expf(a0), w1 = __expf(a1), w2 = __expf(a2), w3 = __expf(a3);
    float w4 = __expf(a4), w5 = __expf(a5), w6 = __expf(a6), w7 = __expf(a7);
    den += ((w0 + w1) + (w2 + w3)) + ((w4 + w5) + (w6 + w7));
    acc += w0 * x0 + w1 * x1 + w2 * x2 + w3 * x3;
    acc += w4 * x4 + w5 * x5 + w6 * x6 + w7 * x7;
  }
  for (; p < end; ++p) {
    int s = srcs[p];
    float a = a_src2[s] + ad;
    a = a >= 0.f ? a : NEG_SLOPE * a;
    float w = __expf(a);
    den += w;
    acc += w * xl2[(size_t)s * 16 + c];
  }
  float o = acc / (den + 1e-16f) + bias2[c];
  o = o > 0.f ? o : expm1f(o);  // ELU alpha=1
  float mx = o;
#pragma unroll
  for (int w = 8; w >= 1; w >>= 1) mx = fmaxf(mx, __shfl_xor(mx, w, 16));
  float e = __expf(o - mx);
  float ssum = e;
#pragma unroll
  for (int w = 8; w >= 1; w >>= 1) ssum += __shfl_xor(ssum, w, 16);
  out[(size_t)node * 16 + c] = o - mx - logf(ssum);
}

extern "C" void kernel_launch(void* const* d_in, const int* in_sizes, int n_in,
                              void* d_out, int out_size, void* d_ws, size_t ws_size,
                              hipStream_t stream) {
  const float* x        = (const float*)d_in[0];
  const int*   ei       = (const int*)d_in[1];
  const float* W1       = (const float*)d_in[2];
  const float* att_src1 = (const float*)d_in[3];
  const float* att_dst1 = (const float*)d_in[4];
  const float* bias1    = (const float*)d_in[5];
  const float* W2       = (const float*)d_in[6];
  const float* att_src2 = (const float*)d_in[7];
  const float* att_dst2 = (const float*)d_in[8];
  const float* bias2    = (const float*)d_in[9];
  float* out = (float*)d_out;

  int N = in_sizes[0] / 512;
  int E = in_sizes[1] / 2;
  int nb = (N + 511) / 512;

  char* ws = (char*)d_ws;
  unsigned short* xlb = (unsigned short*)ws;        ws += (size_t)N * 64 * 2;
  unsigned short* W1t = (unsigned short*)ws;        ws += (size_t)512 * 64 * 2;
  float* a_src1 = (float*)ws;                       ws += (size_t)N * 8 * 4;
  float* a_dst1 = (float*)ws;                       ws += (size_t)N * 8 * 4;
  float* xl2    = (float*)ws;                       ws += (size_t)N * 16 * 4;
  float* a_src2 = (float*)ws;                       ws += (size_t)N * 4;
  float* a_dst2 = (float*)ws;                       ws += (size_t)N * 4;
  int* deg      = (int*)ws;                         ws += (size_t)N * 4;
  int* rowptr   = (int*)ws;                         ws += (size_t)(N + 1) * 4;
  int* cursor   = (int*)ws;                         ws += (size_t)N * 4;
  int* srcs     = (int*)ws;                         ws += (size_t)(E + N) * 4;
  int* partials = (int*)ws;                         ws += (size_t)nb * 4;
  int* blockoff = (int*)ws;                         ws += (size_t)nb * 4;

  const int NCHUNK = 256;
  int ipc_h = (E + NCHUNK - 1) / NCHUNK;
  int ipc_s = (E + N + NCHUNK - 1) / NCHUNK;

  prep_kernel<<<(32768 + N + 255) / 256, 256, 0, stream>>>(W1, W1t, deg, N);
  deg_hist_sliced<<<NCHUNK * 8, 256, 0, stream>>>(ei, deg, E, N, ipc_h);
  partial_sums<<<nb, 256, 0, stream>>>(deg, partials, N);
  scan_partials<<<1, 256, 0, stream>>>(partials, blockoff, rowptr, nb, N);
  scan_blocks<<<nb, 256, 0, stream>>>(deg, blockoff, rowptr, cursor, N);
  scatter_sliced<<<NCHUNK * 8, 256, 0, stream>>>(ei, cursor, srcs, E, N, ipc_s);

  gemm1_mfma<<<(N + 63) / 64, 256, 0, stream>>>(x, W1t, att_src1, att_dst1,
                                                xlb, a_src1, a_dst1, N);
  agg1_fused<<<(N + 3) / 4, 256, 0, stream>>>(rowptr, srcs, a_src1, a_dst1, xlb,
                                              bias1, W2, att_src2, att_dst2,
                                              xl2, a_src2, a_dst2, N);
  agg2_fin<<<((size_t)N * 16 + 255) / 256, 256, 0, stream>>>(rowptr, srcs, a_src2, a_dst2,
                                                             xl2, bias2, out, N);
}